// Round 17
// baseline (727.242 us; speedup 1.0000x reference)
//
#include <hip/hip_runtime.h>
#include <stdint.h>

// Problem constants (fixed by the reference)
#define TOKENS 8192
#define D_IN   1024
#define NEXP   8
#define D_OUT  1024
#define HDIM   2048

typedef __bf16 bf16x8 __attribute__((ext_vector_type(8)));
typedef __bf16 bf16x4 __attribute__((ext_vector_type(4)));
typedef float  f32x4  __attribute__((ext_vector_type(4)));

// ---------------------------------------------------------------------------
__device__ __forceinline__ void gload16(const void* g, void* l) {
  __builtin_amdgcn_global_load_lds(
      (const __attribute__((address_space(1))) void*)g,
      (__attribute__((address_space(3))) void*)l,
      16, 0, 0);
}

template <int N>
__device__ __forceinline__ void waitv() {
  if constexpr (N == 0)      asm volatile("s_waitcnt vmcnt(0)" ::: "memory");
  else if constexpr (N == 1) asm volatile("s_waitcnt vmcnt(1)" ::: "memory");
  else if constexpr (N == 2) asm volatile("s_waitcnt vmcnt(2)" ::: "memory");
  else if constexpr (N == 3) asm volatile("s_waitcnt vmcnt(3)" ::: "memory");
  else if constexpr (N == 4) asm volatile("s_waitcnt vmcnt(4)" ::: "memory");
  else static_assert(N <= 4, "unsupported vmcnt");
}

// ---------------------------------------------------------------------------
// Fused gating + x->bf16 conversion. One wave per token.
__global__ void gate_cvt_kernel(const float* __restrict__ x,
                                const float* __restrict__ Wg,
                                const float* __restrict__ bg,
                                float* __restrict__ gates,
                                __bf16* __restrict__ xb) {
  const int lane = threadIdx.x & 63;
  const int n = blockIdx.x * 4 + (threadIdx.x >> 6);
  float acc[NEXP];
#pragma unroll
  for (int e = 0; e < NEXP; ++e) acc[e] = 0.f;
  const float* xr = x + (size_t)n * D_IN;
  __bf16* xo = xb + (size_t)n * D_IN;
#pragma unroll 4
  for (int d0 = 0; d0 < D_IN; d0 += 64) {
    const int d = d0 + lane;
    float xv = xr[d];
    xo[d] = (__bf16)xv;
    const float* wr = Wg + d * NEXP;
#pragma unroll
    for (int e = 0; e < NEXP; ++e) acc[e] += xv * wr[e];
  }
#pragma unroll
  for (int e = 0; e < NEXP; ++e) {
    float v = acc[e];
#pragma unroll
    for (int off = 32; off > 0; off >>= 1) v += __shfl_down(v, off);
    acc[e] = v;
  }
  if (lane == 0) {
    float mx = -1e30f;
#pragma unroll
    for (int e = 0; e < NEXP; ++e) { acc[e] += bg[e]; mx = fmaxf(mx, acc[e]); }
    float s = 0.f;
#pragma unroll
    for (int e = 0; e < NEXP; ++e) { acc[e] = expf(acc[e] - mx); s += acc[e]; }
    float inv = 1.f / s;
#pragma unroll
    for (int e = 0; e < NEXP; ++e) gates[n * NEXP + e] = acc[e] * inv;
  }
}

// ---------------------------------------------------------------------------
// Transpose-convert: f32 W[e][k][n] -> bf16 Wt[slice = e/EPG][n][(e%EPG)*K + k]
__global__ void transpose_cvt_kernel(const float* __restrict__ W,
                                     __bf16* __restrict__ Wt,
                                     int K, int N, int EPG) {
  __shared__ float tile[32][33];
  const int e = blockIdx.z;
  const int ldo = EPG * K;
  const float* Win = W + (size_t)e * K * N;
  __bf16* Wout = Wt + (size_t)(e / EPG) * N * ldo + (size_t)(e % EPG) * K;
  const int n0 = blockIdx.x * 32;
  const int k0 = blockIdx.y * 32;
  const int tx = threadIdx.x & 31;
  const int ty = threadIdx.x >> 5;
#pragma unroll
  for (int r = ty; r < 32; r += 8)
    tile[r][tx] = Win[(size_t)(k0 + r) * N + n0 + tx];
  __syncthreads();
#pragma unroll
  for (int r = ty; r < 32; r += 8)
    Wout[(size_t)(n0 + r) * ldo + k0 + tx] = (__bf16)tile[tx][r];
}

// ---------------------------------------------------------------------------
// Final merge: out[n][f] += acc1[n][f] + sum_e g[n][e]*b2[e][f]
__global__ void merge_kernel(float* __restrict__ out,
                             const float* __restrict__ acc1,
                             const float* __restrict__ gates,
                             const float* __restrict__ b2) {
  const int idx = blockIdx.x * 256 + threadIdx.x;   // over TOKENS*D_OUT/4
  const int n = idx >> 8;
  const int fb = idx & 255;
  float4 o = ((const float4*)out)[idx];
  float4 a = ((const float4*)acc1)[idx];
  o.x += a.x; o.y += a.y; o.z += a.z; o.w += a.w;
  const float* g = gates + (size_t)n * NEXP;
#pragma unroll
  for (int e = 0; e < NEXP; ++e) {
    const float ge = g[e];
    float4 b = ((const float4*)(b2 + (size_t)e * D_OUT))[fb];
    o.x += ge * b.x; o.y += ge * b.y; o.z += ge * b.z; o.w += ge * b.w;
  }
  ((float4*)out)[idx] = o;
}

// ---------------------------------------------------------------------------
// Rotating-quarter GEMM (R8/R16-verified schedule): D = A[M][Kext]*B[N][Kext]^T
// (row stride LDK), bf16, f32 accum. BK=64, XOR swizzle (row&7)<<4. One LDS
// slot; quarters A0,B0,A1,B1 each have ONE reader phase (p0,p0,p2,p1), are
// restaged in-place 1+ phase after their read; counted vmcnt never 0 mid-loop:
//   p0: read A0,B0 -> mma(0,0); stage A1(t)  ; wait vmcnt(LA)  [drain B1(t)]
//   p1: read B1    -> mma(0,1); stage A0(t+1); wait vmcnt(LA|0)[drain A1(t)]
//   p2: read A1    -> mma(1,0); stage B0(t+1)
//   p3:            -> mma(1,1); stage B1(t+1); wait vmcnt(LB)  [drain A0,B0]
// Geometry: 8-wave 256x256 (per-wave 128x64) or 4-wave 128x128 (per-wave
// 64x64, ~140 regs, WPE=3). GEMM2 occupancy lever: z = K-half parity ->
// 1024-block grid -> 3 blocks/CU (R16 showed grid=512 capped at 2 w/SIMD).
// z-dim: A += z*AZ, B += z*BZ (elements).
// EPI 0 (GEMM1): Hout[row][z*OCZ+col] = bf16(relu(D+b1[e0+z][col])*g[row][e0+z])
// EPI 3 (GEMM2): F = (z ? F1 : F0); F[row][col] (first ? = : +=) D.
template <int NT, int WPE, int BM, int BN, int WM, int WN, int EPI>
__global__ __launch_bounds__(NT, WPE)
void moe_gemm(const __bf16* __restrict__ A, size_t AZ,
              const __bf16* __restrict__ B, size_t BZ,
              const float* __restrict__ b1g,
              const float* __restrict__ gates,
              int e0,
              __bf16* __restrict__ Hout, int OCZ, int ldo,
              float* __restrict__ F0, float* __restrict__ F1,
              int first, int M, int N, int Kext, int LDK) {
  constexpr int RM = BM / WM, RN = BN / WN;
  constexpr int FM = RM / 16, FN = RN / 16;
  constexpr int HM = FM / 2,  HN = FN / 2;
  constexpr int LA = BM * 4 / NT;       // gloads/thread per A-half
  constexpr int LB = BN * 4 / NT;       // gloads/thread per B-half
  constexpr int AELEM = BM * 64;        // A region elems
  static_assert(HM >= 1 && HN >= 1, "tile too small");
  __shared__ alignas(16) __bf16 lds[(BM + BN) * 64];   // ONE slot

  const int tid  = threadIdx.x;
  const int lane = tid & 63;
  const int wave = tid >> 6;
  const int wr   = wave / WN;
  const int wc   = wave % WN;
  const int lrow = lane & 15;
  const int khi  = lane >> 4;
  const int sx   = (lrow & 7) << 3;     // read-side swizzle (elements)
  const int bz   = blockIdx.z;

  A += (size_t)bz * AZ;
  B += (size_t)bz * BZ;

  // XCD-aware bijective block swizzle (per-z nwg divisible by 8)
  const int Gx   = gridDim.x;
  const int nwg  = Gx * gridDim.y;
  const int orig = blockIdx.y * Gx + blockIdx.x;
  const int wgid = (orig & 7) * (nwg >> 3) + (orig >> 3);
  const int bn0  = (wgid % Gx) * BN;
  const int bm0  = (wgid / Gx) * BM;

  // Pre-swizzled global sources: LDS byte o of region holds global column
  // byte (o&127) ^ ((row&7)<<4) of row (o>>7).
  const __bf16* srcA[2][LA];
  const __bf16* srcB[2][LB];
#pragma unroll
  for (int q = 0; q < 2; ++q) {
#pragma unroll
    for (int j = 0; j < LA; ++j) {
      int o   = q * (BM * 64) + j * (NT * 16) + tid * 16;
      int row = o >> 7;
      int cb  = (o & 127) ^ ((row & 7) << 4);
      srcA[q][j] = A + (size_t)(bm0 + row) * LDK + (cb >> 1);
    }
#pragma unroll
    for (int j = 0; j < LB; ++j) {
      int o   = q * (BN * 64) + j * (NT * 16) + tid * 16;
      int row = o >> 7;
      int cb  = (o & 127) ^ ((row & 7) << 4);
      srcB[q][j] = B + (size_t)(bn0 + row) * LDK + (cb >> 1);
    }
  }

  auto stageA = [&](int kt, int q) {
#pragma unroll
    for (int j = 0; j < LA; ++j)
      gload16(srcA[q][j] + (size_t)kt * 64,
              lds + q * (BM * 32) + j * (NT * 8) + wave * 512);
  };
  auto stageB = [&](int kt, int q) {
#pragma unroll
    for (int j = 0; j < LB; ++j)
      gload16(srcB[q][j] + (size_t)kt * 64,
              lds + AELEM + q * (BN * 32) + j * (NT * 8) + wave * 512);
  };

  f32x4 acc[FM][FN];
#pragma unroll
  for (int m = 0; m < FM; ++m)
#pragma unroll
    for (int n = 0; n < FN; ++n) acc[m][n] = f32x4{0.f, 0.f, 0.f, 0.f};

  bf16x8 af[HM][2];       // current mq-half A fragments
  bf16x8 bf[2][HN][2];    // B fragments, cached across the K-tile

  // Fragment rows of half mq live in staged block-half mq (race-free).
  auto rdA = [&](int mq) {
#pragma unroll
    for (int mi = 0; mi < HM; ++mi)
#pragma unroll
      for (int kk = 0; kk < 2; ++kk)
        af[mi][kk] = *(const bf16x8*)
            &lds[(size_t)(mq * (BM / 2) + wr * (RM / 2) + mi * 16 + lrow) * 64 +
                 ((kk * 32 + khi * 8) ^ sx)];
  };
  auto rdB = [&](int nq) {
#pragma unroll
    for (int ni = 0; ni < HN; ++ni)
#pragma unroll
      for (int kk = 0; kk < 2; ++kk)
        bf[nq][ni][kk] = *(const bf16x8*)
            &lds[AELEM +
                 (size_t)(nq * (BN / 2) + wc * (RN / 2) + ni * 16 + lrow) * 64 +
                 ((kk * 32 + khi * 8) ^ sx)];
  };
  auto cluster = [&](int mq, int nq) {
    __builtin_amdgcn_s_setprio(1);
#pragma unroll
    for (int kk = 0; kk < 2; ++kk)
#pragma unroll
      for (int mi = 0; mi < HM; ++mi)
#pragma unroll
        for (int ni = 0; ni < HN; ++ni)
          acc[mq * HM + mi][nq * HN + ni] =
              __builtin_amdgcn_mfma_f32_16x16x32_bf16(
                  af[mi][kk], bf[nq][ni][kk], acc[mq * HM + mi][nq * HN + ni],
                  0, 0, 0);
    __builtin_amdgcn_s_setprio(0);
  };

#define BAR()   asm volatile("s_barrier" ::: "memory")
#define LGKM0() do { asm volatile("s_waitcnt lgkmcnt(0)" ::: "memory"); \
                     __builtin_amdgcn_sched_barrier(0); } while (0)

  const int nk = Kext >> 6;

  // prologue: stage A0(0), B0(0), B1(0); drain A0,B0 (leave B1 in flight)
  stageA(0, 0); stageB(0, 0); stageB(0, 1);
  waitv<LB>();
  BAR();

  for (int t = 0; t < nk; ++t) {
    const bool pf = (t + 1 < nk);

    // p0 : read A0,B0 ; mma(0,0) ; stage A1(t) ; drain B1(t)
    rdA(0); rdB(0);
    stageA(t, 1);
    BAR(); LGKM0();
    cluster(0, 0);
    waitv<LA>();
    BAR();
    // p1 : read B1 ; mma(0,1) ; stage A0(t+1) ; drain A1(t)
    rdB(1);
    if (pf) stageA(t + 1, 0);
    BAR(); LGKM0();
    cluster(0, 1);
    if (pf) waitv<LA>(); else waitv<0>();
    BAR();
    // p2 : read A1 ; mma(1,0) ; stage B0(t+1)
    rdA(1);
    if (pf) stageB(t + 1, 0);
    BAR(); LGKM0();
    cluster(1, 0);
    BAR();
    // p3 : mma(1,1) ; stage B1(t+1) ; drain A0,B0(t+1)
    if (pf) stageB(t + 1, 1);
    BAR();
    cluster(1, 1);
    if (pf) waitv<LB>();
    BAR();
  }

#undef BAR
#undef LGKM0

  // Epilogue. C/D frag: col = lane&15, row = (lane>>4)*4 + reg  [HW-verified]
  const float* bias = (EPI == 0) ? b1g + (size_t)(e0 + bz) * HDIM : nullptr;
  const int ecol = e0 + bz;
  __bf16* Hp = (EPI == 0) ? Hout + (size_t)bz * OCZ : nullptr;
  float* F = (EPI == 3) ? (bz ? F1 : F0) : nullptr;

#pragma unroll
  for (int m = 0; m < FM; ++m) {
    const int grow0 = bm0 + (m / HM) * (BM / 2) + wr * (RM / 2) +
                      (m % HM) * 16 + khi * 4;
    if constexpr (EPI == 0) {
      float g[4];
#pragma unroll
      for (int r = 0; r < 4; ++r)
        g[r] = gates[(size_t)(grow0 + r) * NEXP + ecol];
#pragma unroll
      for (int n = 0; n < FN; ++n) {
        const int gcol = bn0 + (n / HN) * (BN / 2) + wc * (RN / 2) +
                         (n % HN) * 16 + lrow;
        const float bv = bias[gcol];
        f32x4 a = acc[m][n];
#pragma unroll
        for (int r = 0; r < 4; ++r) {
          float v = a[r] + bv;
          v = v > 0.f ? v : 0.f;
          Hp[(size_t)(grow0 + r) * ldo + gcol] = (__bf16)(v * g[r]);
        }
      }
    } else {
#pragma unroll
      for (int n = 0; n < FN; ++n) {
        const int gcol = bn0 + (n / HN) * (BN / 2) + wc * (RN / 2) +
                         (n % HN) * 16 + lrow;
        f32x4 a = acc[m][n];
#pragma unroll
        for (int r = 0; r < 4; ++r) {
          float* o = F + (size_t)(grow0 + r) * N + gcol;
          if (first) *o = a[r];
          else       *o += a[r];
        }
      }
    }
  }
}

// ---------------------------------------------------------------------------
extern "C" void kernel_launch(void* const* d_in, const int* in_sizes, int n_in,
                              void* d_out, int out_size, void* d_ws, size_t ws_size,
                              hipStream_t stream) {
  const float* x  = (const float*)d_in[0];
  const float* W1 = (const float*)d_in[1];
  const float* b1 = (const float*)d_in[2];
  const float* W2 = (const float*)d_in[3];
  const float* b2 = (const float*)d_in[4];
  const float* Wg = (const float*)d_in[5];
  const float* bg = (const float*)d_in[6];
  float* out = (float*)d_out;

  // ws layout
  char* w = (char*)d_ws;
  float* gates = (float*)w;   w += (size_t)TOKENS * NEXP * 4;       //   0.25 MB
  __bf16* xb   = (__bf16*)w;  w += (size_t)TOKENS * D_IN * 2;       //  16 MB
  __bf16* w1t  = (__bf16*)w;  w += (size_t)NEXP * HDIM * D_IN * 2;  //  32 MB
  __bf16* w2c  = (__bf16*)w;  w += (size_t)NEXP * D_OUT * HDIM * 2; //  32 MB
  float* acc1  = (float*)w;   w += (size_t)TOKENS * D_OUT * 4;      //  32 MB
  const size_t base = (size_t)(w - (char*)d_ws);

  const size_t h1_b = (size_t)TOKENS * HDIM * 2;   // 32 MB per expert
  const int G = (ws_size >= base + 4 * h1_b) ? 4
              : (ws_size >= base + 2 * h1_b) ? 2 : 1;
  __bf16* hbuf = (__bf16*)w;   // [TOKENS][G*2048] concatenated-K layout

  const size_t WSLICE = (size_t)HDIM * D_IN;   // w1t per-expert elems
  const int KB = G * HDIM;                     // GEMM2 K per group
  const int KH = KB / 2;                       // GEMM2 K per z-half

  gate_cvt_kernel<<<TOKENS / 4, 256, 0, stream>>>(x, Wg, bg, gates, xb);
  transpose_cvt_kernel<<<dim3(HDIM / 32, D_IN / 32, NEXP), 256, 0, stream>>>(
      W1, w1t, D_IN, HDIM, 1);
  // W2: [E][H][D_OUT] -> w2c[e/G][n][(e%G)*H + k]  (LDK = G*H, matches hbuf)
  transpose_cvt_kernel<<<dim3(D_OUT / 32, HDIM / 32, NEXP), 256, 0, stream>>>(
      W2, w2c, HDIM, D_OUT, G);

  const int ngroups = NEXP / G;
  for (int d = 0; d < ngroups; ++d) {
    // GEMM1: fill hbuf[*][0..KB) with experts G*d .. G*d+G-1 (column bands)
    if (G >= 2) {
      for (int i2 = 0; i2 < G / 2; ++i2) {
        const int e0 = G * d + 2 * i2;
        moe_gemm<512, 2, 256, 256, 2, 4, 0><<<dim3(8, 32, 2), 512, 0, stream>>>(
            xb, 0, w1t + (size_t)e0 * WSLICE, WSLICE, b1, gates, e0,
            hbuf + (size_t)i2 * 2 * HDIM, HDIM, KB,
            nullptr, nullptr, 0, TOKENS, HDIM, D_IN, D_IN);
      }
    } else {
      moe_gemm<512, 2, 256, 256, 2, 4, 0><<<dim3(8, 32, 1), 512, 0, stream>>>(
          xb, 0, w1t + (size_t)d * WSLICE, 0, b1, gates, d,
          hbuf, 0, KB,
          nullptr, nullptr, 0, TOKENS, HDIM, D_IN, D_IN);
    }
    // GEMM2: 4-wave 128x128, z = K-half parity (z0->out, z1->acc1):
    // grid (8,64,2) = 1024 blocks -> 3 blocks/CU (vs R16's 512 -> 2/CU).
    moe_gemm<256, 3, 128, 128, 2, 2, 3><<<dim3(D_OUT / 128, TOKENS / 128, 2),
                                          256, 0, stream>>>(
        hbuf, (size_t)KH, w2c + (size_t)d * D_OUT * KB, (size_t)KH,
        nullptr, nullptr, 0, nullptr, 0, 0,
        out, acc1, (d == 0) ? 1 : 0, TOKENS, D_OUT, KH, KB);
  }

  merge_kernel<<<TOKENS, 256, 0, stream>>>(out, acc1, gates, b2);
}

// Round 18
// 653.901 us; speedup vs baseline: 1.1122x; 1.1122x over previous
//
#include <hip/hip_runtime.h>
#include <stdint.h>

// Problem constants (fixed by the reference)
#define TOKENS 8192
#define D_IN   1024
#define NEXP   8
#define D_OUT  1024
#define HDIM   2048

typedef __bf16 bf16x8 __attribute__((ext_vector_type(8)));
typedef __bf16 bf16x4 __attribute__((ext_vector_type(4)));
typedef float  f32x4  __attribute__((ext_vector_type(4)));

// ---------------------------------------------------------------------------
__device__ __forceinline__ void gload16(const void* g, void* l) {
  __builtin_amdgcn_global_load_lds(
      (const __attribute__((address_space(1))) void*)g,
      (__attribute__((address_space(3))) void*)l,
      16, 0, 0);
}

template <int N>
__device__ __forceinline__ void waitv() {
  if constexpr (N == 0)      asm volatile("s_waitcnt vmcnt(0)" ::: "memory");
  else if constexpr (N == 1) asm volatile("s_waitcnt vmcnt(1)" ::: "memory");
  else if constexpr (N == 2) asm volatile("s_waitcnt vmcnt(2)" ::: "memory");
  else if constexpr (N == 3) asm volatile("s_waitcnt vmcnt(3)" ::: "memory");
  else if constexpr (N == 4) asm volatile("s_waitcnt vmcnt(4)" ::: "memory");
  else if constexpr (N == 8) asm volatile("s_waitcnt vmcnt(8)" ::: "memory");
  else static_assert(N <= 8, "unsupported vmcnt");
}

// ---------------------------------------------------------------------------
// Fused gating + x->bf16 conversion. One wave per token.
__global__ void gate_cvt_kernel(const float* __restrict__ x,
                                const float* __restrict__ Wg,
                                const float* __restrict__ bg,
                                float* __restrict__ gates,
                                __bf16* __restrict__ xb) {
  const int lane = threadIdx.x & 63;
  const int n = blockIdx.x * 4 + (threadIdx.x >> 6);
  float acc[NEXP];
#pragma unroll
  for (int e = 0; e < NEXP; ++e) acc[e] = 0.f;
  const float* xr = x + (size_t)n * D_IN;
  __bf16* xo = xb + (size_t)n * D_IN;
#pragma unroll 4
  for (int d0 = 0; d0 < D_IN; d0 += 64) {
    const int d = d0 + lane;
    float xv = xr[d];
    xo[d] = (__bf16)xv;
    const float* wr = Wg + d * NEXP;
#pragma unroll
    for (int e = 0; e < NEXP; ++e) acc[e] += xv * wr[e];
  }
#pragma unroll
  for (int e = 0; e < NEXP; ++e) {
    float v = acc[e];
#pragma unroll
    for (int off = 32; off > 0; off >>= 1) v += __shfl_down(v, off);
    acc[e] = v;
  }
  if (lane == 0) {
    float mx = -1e30f;
#pragma unroll
    for (int e = 0; e < NEXP; ++e) { acc[e] += bg[e]; mx = fmaxf(mx, acc[e]); }
    float s = 0.f;
#pragma unroll
    for (int e = 0; e < NEXP; ++e) { acc[e] = expf(acc[e] - mx); s += acc[e]; }
    float inv = 1.f / s;
#pragma unroll
    for (int e = 0; e < NEXP; ++e) gates[n * NEXP + e] = acc[e] * inv;
  }
}

// ---------------------------------------------------------------------------
// Transpose-convert: f32 W[e][k][n] -> bf16 Wt[slice = e/EPG][n][(e%EPG)*K + k]
__global__ void transpose_cvt_kernel(const float* __restrict__ W,
                                     __bf16* __restrict__ Wt,
                                     int K, int N, int EPG) {
  __shared__ float tile[32][33];
  const int e = blockIdx.z;
  const int ldo = EPG * K;
  const float* Win = W + (size_t)e * K * N;
  __bf16* Wout = Wt + (size_t)(e / EPG) * N * ldo + (size_t)(e % EPG) * K;
  const int n0 = blockIdx.x * 32;
  const int k0 = blockIdx.y * 32;
  const int tx = threadIdx.x & 31;
  const int ty = threadIdx.x >> 5;
#pragma unroll
  for (int r = ty; r < 32; r += 8)
    tile[r][tx] = Win[(size_t)(k0 + r) * N + n0 + tx];
  __syncthreads();
#pragma unroll
  for (int r = ty; r < 32; r += 8)
    Wout[(size_t)(n0 + r) * ldo + k0 + tx] = (__bf16)tile[tx][r];
}

// ---------------------------------------------------------------------------
// Final merge: out[n][f] += sum_e g[n][e]*b2[e][f]
__global__ void merge_kernel(float* __restrict__ out,
                             const float* __restrict__ gates,
                             const float* __restrict__ b2) {
  const int idx = blockIdx.x * 256 + threadIdx.x;   // over TOKENS*D_OUT/4
  const int n = idx >> 8;
  const int fb = idx & 255;
  float4 o = ((const float4*)out)[idx];
  const float* g = gates + (size_t)n * NEXP;
#pragma unroll
  for (int e = 0; e < NEXP; ++e) {
    const float ge = g[e];
    float4 b = ((const float4*)(b2 + (size_t)e * D_OUT))[fb];
    o.x += ge * b.x; o.y += ge * b.y; o.z += ge * b.z; o.w += ge * b.w;
  }
  ((float4*)out)[idx] = o;
}

// ---------------------------------------------------------------------------
// Rotating-quarter GEMM: D = A[M][K]*B[N][K]^T, bf16, f32 accum. BK=64,
// XOR swizzle (row&7)<<4 on the LDS layout.
//
// RSTG=0 (R8/R16-verified): gload_lds staging with pre-swizzled sources, one
//   LDS slot, 4 phases/K-tile, counted vmcnt.
// RSTG=1 (NEW, coalesced): global_load_dwordx4 with LINEAR lane addresses
//   (the pre-swizzled gload_lds source scatters 16B chunks within each 128B
//   line and pins the fetch path at ~1 TB/s; R1's near-linear sources hit
//   2.25 TB/s) -> NAMED float4 registers (two sets SA/SB; no arrays, no
//   address-taken locals — R14's scratch / R15's budget failures audited out;
//   this geometry: 64 AGPR acc + ~160 VGPR < 256 @ launch_bounds(NT,2)) ->
//   ds_write_b128 at swizzled offsets (write perm stays within 128B rows ->
//   2-way, free; frag reads unchanged). 2 slots, 1 barrier/K-tile, 32-MFMA
//   clusters. Iter t (slot s=t&1): {rd A0+allB; issue L(t+2)->set(t&1);
//   lgkm0; MFMA half0; rd A1; vmcnt(8) [L(t+1) landed]; ds_write L(t+1)->
//   slot s^1; lgkm0; MFMA half1; BAR}. FIFO: queue 8<->16, steady vmcnt(8),
//   never 0 mid-loop (except tails). Race-free: write-slot != read-slot;
//   lgkm0 precedes the publishing barrier.
// EPI 0 (GEMM1): Hout[row][z*OCZ+col] = bf16(relu(D+b1[e0+z][col])*g[row][e0+z])
// EPI 3 (GEMM2): F0[row][col] (first ? = : +=) D.
template <int NT, int WPE, int BM, int BN, int WM, int WN, int EPI, int RSTG>
__global__ __launch_bounds__(NT, WPE)
void moe_gemm(const __bf16* __restrict__ A, size_t AZ,
              const __bf16* __restrict__ B, size_t BZ,
              const float* __restrict__ b1g,
              const float* __restrict__ gates,
              int e0,
              __bf16* __restrict__ Hout, int OCZ, int ldo,
              float* __restrict__ F0,
              int first, int M, int N, int K) {
  constexpr int RM = BM / WM, RN = BN / WN;
  constexpr int FM = RM / 16, FN = RN / 16;
  constexpr int HM = FM / 2,  HN = FN / 2;
  constexpr int LA = BM * 4 / NT;       // loads/thread per A-half
  constexpr int LB = BN * 4 / NT;       // loads/thread per B-half
  constexpr int AELEM = BM * 64;        // A region elems per slot
  constexpr int SLOT  = (BM + BN) * 64; // elems per slot
  constexpr int NSLOT = (RSTG == 0) ? 1 : 2;
  static_assert(HM >= 1 && HN >= 1, "tile too small");
  __shared__ alignas(16) __bf16 lds[NSLOT * SLOT];

  const int tid  = threadIdx.x;
  const int lane = tid & 63;
  const int wave = tid >> 6;
  const int wr   = wave / WN;
  const int wc   = wave % WN;
  const int lrow = lane & 15;
  const int khi  = lane >> 4;
  const int sx   = (lrow & 7) << 3;     // read-side swizzle (elements)
  const int bz   = blockIdx.z;

  A += (size_t)bz * AZ;
  B += (size_t)bz * BZ;

  // XCD-aware bijective block swizzle (per-z nwg divisible by 8)
  const int Gx   = gridDim.x;
  const int nwg  = Gx * gridDim.y;
  const int orig = blockIdx.y * Gx + blockIdx.x;
  const int wgid = (orig & 7) * (nwg >> 3) + (orig >> 3);
  const int bn0  = (wgid % Gx) * BN;
  const int bm0  = (wgid / Gx) * BM;

  f32x4 acc[FM][FN];
#pragma unroll
  for (int m = 0; m < FM; ++m)
#pragma unroll
    for (int n = 0; n < FN; ++n) acc[m][n] = f32x4{0.f, 0.f, 0.f, 0.f};

  bf16x8 af[HM][2];       // current mq-half A fragments
  bf16x8 bf[2][HN][2];    // B fragments, cached across the K-tile

  // Fragment rows of half mq live in staged block-half mq (race-free).
  auto rdA = [&](const __bf16* As, int mq) {
#pragma unroll
    for (int mi = 0; mi < HM; ++mi)
#pragma unroll
      for (int kk = 0; kk < 2; ++kk)
        af[mi][kk] = *(const bf16x8*)
            &As[(size_t)(mq * (BM / 2) + wr * (RM / 2) + mi * 16 + lrow) * 64 +
                ((kk * 32 + khi * 8) ^ sx)];
  };
  auto rdB = [&](const __bf16* Bs, int nq) {
#pragma unroll
    for (int ni = 0; ni < HN; ++ni)
#pragma unroll
      for (int kk = 0; kk < 2; ++kk)
        bf[nq][ni][kk] = *(const bf16x8*)
            &Bs[(size_t)(nq * (BN / 2) + wc * (RN / 2) + ni * 16 + lrow) * 64 +
                ((kk * 32 + khi * 8) ^ sx)];
  };
  auto cluster = [&](int mq, int nq) {
    __builtin_amdgcn_s_setprio(1);
#pragma unroll
    for (int kk = 0; kk < 2; ++kk)
#pragma unroll
      for (int mi = 0; mi < HM; ++mi)
#pragma unroll
        for (int ni = 0; ni < HN; ++ni)
          acc[mq * HM + mi][nq * HN + ni] =
              __builtin_amdgcn_mfma_f32_16x16x32_bf16(
                  af[mi][kk], bf[nq][ni][kk], acc[mq * HM + mi][nq * HN + ni],
                  0, 0, 0);
    __builtin_amdgcn_s_setprio(0);
  };
  auto cluster_h = [&](int mq) {
    __builtin_amdgcn_s_setprio(1);
#pragma unroll
    for (int kk = 0; kk < 2; ++kk)
#pragma unroll
      for (int mi = 0; mi < HM; ++mi)
#pragma unroll
        for (int nq = 0; nq < 2; ++nq)
#pragma unroll
          for (int ni = 0; ni < HN; ++ni)
            acc[mq * HM + mi][nq * HN + ni] =
                __builtin_amdgcn_mfma_f32_16x16x32_bf16(
                    af[mi][kk], bf[nq][ni][kk], acc[mq * HM + mi][nq * HN + ni],
                    0, 0, 0);
    __builtin_amdgcn_s_setprio(0);
  };

#define BAR()   asm volatile("s_barrier" ::: "memory")
#define LGKM0() do { asm volatile("s_waitcnt lgkmcnt(0)" ::: "memory"); \
                     __builtin_amdgcn_sched_barrier(0); } while (0)

  const int nk = K >> 6;

  if constexpr (RSTG == 0) {
    // ---- R8/R16-verified single-slot 4-phase schedule ----
    const __bf16* srcA[2][LA];
    const __bf16* srcB[2][LB];
#pragma unroll
    for (int q = 0; q < 2; ++q) {
#pragma unroll
      for (int j = 0; j < LA; ++j) {
        int o   = q * (BM * 64) + j * (NT * 16) + tid * 16;
        int row = o >> 7;
        int cb  = (o & 127) ^ ((row & 7) << 4);
        srcA[q][j] = A + (size_t)(bm0 + row) * K + (cb >> 1);
      }
#pragma unroll
      for (int j = 0; j < LB; ++j) {
        int o   = q * (BN * 64) + j * (NT * 16) + tid * 16;
        int row = o >> 7;
        int cb  = (o & 127) ^ ((row & 7) << 4);
        srcB[q][j] = B + (size_t)(bn0 + row) * K + (cb >> 1);
      }
    }
    auto stageA = [&](int kt, int q) {
#pragma unroll
      for (int j = 0; j < LA; ++j)
        gload16(srcA[q][j] + (size_t)kt * 64,
                lds + q * (BM * 32) + j * (NT * 8) + wave * 512);
    };
    auto stageB = [&](int kt, int q) {
#pragma unroll
      for (int j = 0; j < LB; ++j)
        gload16(srcB[q][j] + (size_t)kt * 64,
                lds + AELEM + q * (BN * 32) + j * (NT * 8) + wave * 512);
    };

    stageA(0, 0); stageB(0, 0); stageB(0, 1);
    waitv<LB>();
    BAR();
    for (int t = 0; t < nk; ++t) {
      const bool pf = (t + 1 < nk);
      rdA(lds, 0); rdB(lds + AELEM, 0);
      stageA(t, 1);
      BAR(); LGKM0();
      cluster(0, 0);
      waitv<LA>();
      BAR();
      rdB(lds + AELEM, 1);
      if (pf) stageA(t + 1, 0);
      BAR(); LGKM0();
      cluster(0, 1);
      if (pf) waitv<LA>(); else waitv<0>();
      BAR();
      rdA(lds, 1);
      if (pf) stageB(t + 1, 0);
      BAR(); LGKM0();
      cluster(1, 0);
      BAR();
      if (pf) stageB(t + 1, 1);
      BAR();
      cluster(1, 1);
      if (pf) waitv<LB>();
      BAR();
    }
  } else {
    // ---- RSTG=1: coalesced reg-staged pipeline (named registers only) ----
    static_assert(LA == 2 && LB == 2, "RSTG sized for 128x128 @256 thr");
    // 8 named linear sources + 8 named swizzled LDS byte offsets.
    const __bf16 *sl0, *sl1, *sl2, *sl3, *sl4, *sl5, *sl6, *sl7;
    int dz0, dz1, dz2, dz3, dz4, dz5, dz6, dz7;
#define MKSRC(i, SL, DZ)                                                       \
  do {                                                                         \
    int o    = (i) * (NT * 16) + tid * 16;                                     \
    bool isA = (o < BM * 128);                                                 \
    int oo   = isA ? o : (o - BM * 128);                                       \
    int row  = oo >> 7;                                                        \
    int cbl  = oo & 127;                                                       \
    SL = (isA ? A + (size_t)(bm0 + row) * K                                    \
              : B + (size_t)(bn0 + row) * K) + (cbl >> 1);                     \
    DZ = (isA ? 0 : BM * 128) + ((oo & ~127) | (cbl ^ ((row & 7) << 4)));      \
  } while (0)
    MKSRC(0, sl0, dz0); MKSRC(1, sl1, dz1); MKSRC(2, sl2, dz2);
    MKSRC(3, sl3, dz3); MKSRC(4, sl4, dz4); MKSRC(5, sl5, dz5);
    MKSRC(6, sl6, dz6); MKSRC(7, sl7, dz7);
#undef MKSRC

    float4 SA0, SA1, SA2, SA3, SA4, SA5, SA6, SA7;
    float4 SB0, SB1, SB2, SB3, SB4, SB5, SB6, SB7;
#define ISSUE8(kt, P)                                                          \
  do {                                                                         \
    P##0 = *(const float4*)(sl0 + (size_t)(kt) * 64);                          \
    P##1 = *(const float4*)(sl1 + (size_t)(kt) * 64);                          \
    P##2 = *(const float4*)(sl2 + (size_t)(kt) * 64);                          \
    P##3 = *(const float4*)(sl3 + (size_t)(kt) * 64);                          \
    P##4 = *(const float4*)(sl4 + (size_t)(kt) * 64);                          \
    P##5 = *(const float4*)(sl5 + (size_t)(kt) * 64);                          \
    P##6 = *(const float4*)(sl6 + (size_t)(kt) * 64);                          \
    P##7 = *(const float4*)(sl7 + (size_t)(kt) * 64);                          \
  } while (0)
#define WST8(sbyte, P)                                                         \
  do {                                                                         \
    char* b_ = (char*)lds + (sbyte);                                           \
    *(float4*)(b_ + dz0) = P##0; *(float4*)(b_ + dz1) = P##1;                  \
    *(float4*)(b_ + dz2) = P##2; *(float4*)(b_ + dz3) = P##3;                  \
    *(float4*)(b_ + dz4) = P##4; *(float4*)(b_ + dz5) = P##5;                  \
    *(float4*)(b_ + dz6) = P##6; *(float4*)(b_ + dz7) = P##7;                  \
  } while (0)

    // prologue: tile0 -> SA -> slot0 ; tile1 -> SB (stays in flight)
    ISSUE8(0, SA);
    ISSUE8(1, SB);
    waitv<8>();          // SA landed (FIFO); SB in flight
    WST8(0, SA);
    LGKM0();
    BAR();               // slot 0 published

    const int half = nk >> 1;   // nk even for all our K
    for (int tt = 0; tt < half; ++tt) {
      {  // ---- even t = 2tt : read slot 0 ; issue->SA ; write SB -> slot 1
        const int t = 2 * tt;
        const __bf16* As = lds;
        const __bf16* Bs = lds + AELEM;
        const bool pf2 = (t + 2 < nk);
        rdA(As, 0); rdB(Bs, 0); rdB(Bs, 1);
        if (pf2) ISSUE8(t + 2, SA);
        LGKM0();
        cluster_h(0);
        rdA(As, 1);
        if (pf2) waitv<8>(); else waitv<0>();   // SB(t+1) regs landed
        WST8(SLOT * 2, SB);                     // A(t+1)|B(t+1) -> slot 1
        LGKM0();
        cluster_h(1);
        BAR();                                  // publish slot 1
      }
      {  // ---- odd t = 2tt+1 : read slot 1 ; issue->SB ; write SA -> slot 0
        const int t = 2 * tt + 1;
        const __bf16* As = lds + SLOT;
        const __bf16* Bs = As + AELEM;
        const bool pf2 = (t + 2 < nk);
        const bool pf1 = (t + 1 < nk);
        rdA(As, 0); rdB(Bs, 0); rdB(Bs, 1);
        if (pf2) ISSUE8(t + 2, SB);
        LGKM0();
        cluster_h(0);
        rdA(As, 1);
        if (pf2) waitv<8>(); else if (pf1) waitv<0>();
        if (pf1) WST8(0, SA);                   // tile t+1 -> slot 0
        LGKM0();
        cluster_h(1);
        BAR();                                  // publish slot 0
      }
    }
#undef ISSUE8
#undef WST8
  }

#undef BAR
#undef LGKM0

  // Epilogue. C/D frag: col = lane&15, row = (lane>>4)*4 + reg  [HW-verified]
  const float* bias = (EPI == 0) ? b1g + (size_t)(e0 + bz) * HDIM : nullptr;
  const int ecol = e0 + bz;
  __bf16* Hp = (EPI == 0) ? Hout + (size_t)bz * OCZ : nullptr;

#pragma unroll
  for (int m = 0; m < FM; ++m) {
    const int grow0 = bm0 + (m / HM) * (BM / 2) + wr * (RM / 2) +
                      (m % HM) * 16 + khi * 4;
    if constexpr (EPI == 0) {
      float g[4];
#pragma unroll
      for (int r = 0; r < 4; ++r)
        g[r] = gates[(size_t)(grow0 + r) * NEXP + ecol];
#pragma unroll
      for (int n = 0; n < FN; ++n) {
        const int gcol = bn0 + (n / HN) * (BN / 2) + wc * (RN / 2) +
                         (n % HN) * 16 + lrow;
        const float bv = bias[gcol];
        f32x4 a = acc[m][n];
#pragma unroll
        for (int r = 0; r < 4; ++r) {
          float v = a[r] + bv;
          v = v > 0.f ? v : 0.f;
          Hp[(size_t)(grow0 + r) * ldo + gcol] = (__bf16)(v * g[r]);
        }
      }
    } else {
#pragma unroll
      for (int n = 0; n < FN; ++n) {
        const int gcol = bn0 + (n / HN) * (BN / 2) + wc * (RN / 2) +
                         (n % HN) * 16 + lrow;
        f32x4 a = acc[m][n];
#pragma unroll
        for (int r = 0; r < 4; ++r) {
          float* o = F0 + (size_t)(grow0 + r) * N + gcol;
          if (first) *o = a[r];
          else       *o += a[r];
        }
      }
    }
  }
}

// ---------------------------------------------------------------------------
extern "C" void kernel_launch(void* const* d_in, const int* in_sizes, int n_in,
                              void* d_out, int out_size, void* d_ws, size_t ws_size,
                              hipStream_t stream) {
  const float* x  = (const float*)d_in[0];
  const float* W1 = (const float*)d_in[1];
  const float* b1 = (const float*)d_in[2];
  const float* W2 = (const float*)d_in[3];
  const float* b2 = (const float*)d_in[4];
  const float* Wg = (const float*)d_in[5];
  const float* bg = (const float*)d_in[6];
  float* out = (float*)d_out;

  // ws layout
  char* w = (char*)d_ws;
  float* gates = (float*)w;   w += (size_t)TOKENS * NEXP * 4;       //   0.25 MB
  __bf16* xb   = (__bf16*)w;  w += (size_t)TOKENS * D_IN * 2;       //  16 MB
  __bf16* w1t  = (__bf16*)w;  w += (size_t)NEXP * HDIM * D_IN * 2;  //  32 MB
  __bf16* w2c  = (__bf16*)w;  w += (size_t)NEXP * D_OUT * HDIM * 2; //  32 MB
  const size_t base = (size_t)(w - (char*)d_ws);

  const size_t h1_b = (size_t)TOKENS * HDIM * 2;   // 32 MB per expert
  const int G = (ws_size >= base + 4 * h1_b) ? 4
              : (ws_size >= base + 2 * h1_b) ? 2 : 1;
  __bf16* hbuf = (__bf16*)w;   // [TOKENS][G*2048] concatenated-K layout

  const size_t WSLICE = (size_t)HDIM * D_IN;   // w1t per-expert elems
  const int KB = G * HDIM;                     // GEMM2 K per group

  gate_cvt_kernel<<<TOKENS / 4, 256, 0, stream>>>(x, Wg, bg, gates, xb);
  transpose_cvt_kernel<<<dim3(HDIM / 32, D_IN / 32, NEXP), 256, 0, stream>>>(
      W1, w1t, D_IN, HDIM, 1);
  // W2: [E][H][D_OUT] -> w2c[e/G][n][(e%G)*H + k]  (LDK = G*H, matches hbuf)
  transpose_cvt_kernel<<<dim3(D_OUT / 32, HDIM / 32, NEXP), 256, 0, stream>>>(
      W2, w2c, HDIM, D_OUT, G);

  const int ngroups = NEXP / G;
  for (int d = 0; d < ngroups; ++d) {
    // GEMM1: fill hbuf[*][0..KB) with experts G*d .. G*d+G-1 (column bands)
    if (G >= 2) {
      for (int i2 = 0; i2 < G / 2; ++i2) {
        const int e0 = G * d + 2 * i2;
        moe_gemm<512, 2, 256, 256, 2, 4, 0, 0>
            <<<dim3(8, 32, 2), 512, 0, stream>>>(
            xb, 0, w1t + (size_t)e0 * WSLICE, WSLICE, b1, gates, e0,
            hbuf + (size_t)i2 * 2 * HDIM, HDIM, KB,
            nullptr, 0, TOKENS, HDIM, D_IN);
      }
    } else {
      moe_gemm<512, 2, 256, 256, 2, 4, 0, 0>
          <<<dim3(8, 32, 1), 512, 0, stream>>>(
          xb, 0, w1t + (size_t)d * WSLICE, 0, b1, gates, d,
          hbuf, 0, KB,
          nullptr, 0, TOKENS, HDIM, D_IN);
    }
    // GEMM2: 4-wave 128x128, coalesced reg-staged pipeline (RSTG=1);
    // single K = G*2048 contiguous GEMM; grid 8x64 = 512 blocks (R16 config)
    moe_gemm<256, 2, 128, 128, 2, 2, 3, 1>
        <<<dim3(D_OUT / 128, TOKENS / 128, 1), 256, 0, stream>>>(
        hbuf, 0, w2c + (size_t)d * D_OUT * KB, 0,
        nullptr, nullptr, 0, nullptr, 0, 0,
        out, (d == 0) ? 1 : 0, TOKENS, D_OUT, KB);
  }

  merge_kernel<<<TOKENS, 256, 0, stream>>>(out, gates, b2);
}